// Round 2
// baseline (599.486 us; speedup 1.0000x reference)
//
#include <hip/hip_runtime.h>
#include <hip/hip_bf16.h>

#define NN 384
#define HIDDIM 128
#define NHEADS 8
#define HD 16
#define LOCAL_E (NN*NN)          // 147456
#define NE (2*LOCAL_E)           // 294912 edges
#define NTILES (NE/16)           // 18432 16-row tiles
#define NWAVES_K2 4096           // 512 blocks * 8 waves

typedef __attribute__((ext_vector_type(8))) __bf16 bf16x8;
typedef __attribute__((ext_vector_type(4))) float f32x4;

// ---------------------------------------------------------------------------
// prep: pack [W_edge | W_gate] (128x256 fp32) into bf16 MFMA B-fragment
// granules: Wg[(cg*4 + kk)*64 + lane], lane=(quad*16+n16), content
// W_cat[k = kk*32 + quad*8 + j][col = cg*16 + n16]. cg<8 -> W_edge head cg,
// cg>=8 -> W_gate head cg-8.
// ---------------------------------------------------------------------------
__global__ void prep_w(const float* __restrict__ W_edge, const float* __restrict__ W_gate,
                       bf16x8* __restrict__ Wg) {
    int gid = blockIdx.x * blockDim.x + threadIdx.x;   // 0..4095
    int n16  = gid & 15;
    int quad = (gid >> 4) & 3;
    int kk   = (gid >> 6) & 3;
    int cg   = gid >> 8;
    int col = cg * 16 + n16;
    int k0 = kk * 32 + quad * 8;
    const float* src = (col < 128) ? (W_edge + col) : (W_gate + (col - 128));
    bf16x8 v;
#pragma unroll
    for (int j = 0; j < 8; ++j) v[j] = (__bf16)src[(size_t)(k0 + j) * 128];
    Wg[gid] = v;
}

// ---------------------------------------------------------------------------
// K1: h = nf@W_node + b ; Q/K/V = h@W_{q,k,v} + b   (fp32, tiny)
// Q/K/V stored as (B, NH, N, HD). 8 rows per 128-thr block.
// ---------------------------------------------------------------------------
__global__ __launch_bounds__(128) void k1_proj(
    const float* __restrict__ nf,
    const float* __restrict__ Wn, const float* __restrict__ bn,
    const float* __restrict__ Wq, const float* __restrict__ bq,
    const float* __restrict__ Wk, const float* __restrict__ bk,
    const float* __restrict__ Wv, const float* __restrict__ bv,
    float* __restrict__ h_res, float* __restrict__ Q,
    float* __restrict__ K, float* __restrict__ V)
{
    __shared__ float xf[8][128];
    __shared__ float hf[8][128];
    int t = threadIdx.x;
    int r0 = blockIdx.x * 8;
    for (int r = 0; r < 8; ++r) xf[r][t] = nf[(size_t)(r0 + r) * 128 + t];
    __syncthreads();
    float acc[8];
#pragma unroll
    for (int r = 0; r < 8; ++r) acc[r] = bn[t];
    for (int k = 0; k < 128; ++k) {
        float w = Wn[k * 128 + t];
#pragma unroll
        for (int r = 0; r < 8; ++r) acc[r] += xf[r][k] * w;
    }
    for (int r = 0; r < 8; ++r) { h_res[(size_t)(r0 + r) * 128 + t] = acc[r]; hf[r][t] = acc[r]; }
    __syncthreads();
    const float* Ws[3] = {Wq, Wk, Wv};
    const float* bs[3] = {bq, bk, bv};
    float* Os[3] = {Q, K, V};
#pragma unroll
    for (int m = 0; m < 3; ++m) {
        float a2[8];
#pragma unroll
        for (int r = 0; r < 8; ++r) a2[r] = bs[m][t];
        for (int k = 0; k < 128; ++k) {
            float w = Ws[m][k * 128 + t];
#pragma unroll
            for (int r = 0; r < 8; ++r) a2[r] += hf[r][k] * w;
        }
        int hh = t >> 4, d = t & 15;
        for (int r = 0; r < 8; ++r) {
            int g = r0 + r;
            int b = g / NN, i = g - b * NN;
            Os[m][(size_t)((b * NHEADS + hh) * NN + i) * HD + d] = a2[r];
        }
    }
}

// ---------------------------------------------------------------------------
// K2: ea[b,h,i,j] = masked( sum_d (E@We+be)*sigmoid(E@Wg+bg) )
// Persistent-B: all 256 weight cols (bf16 fragments, 64 KB) in LDS, loaded
// once per block. Each wave independently streams 16-row A tiles
// global->regs->bf16 with 1-tile prefetch. No barriers in the main loop.
// ---------------------------------------------------------------------------
__global__ __launch_bounds__(512, 2) void k2_edge(
    const float* __restrict__ EF, const bf16x8* __restrict__ Wg,
    const float* __restrict__ b_edge, const float* __restrict__ b_gate,
    const int* __restrict__ adj, float* __restrict__ ea)
{
    __shared__ bf16x8 Bsh[4096];   // 64 KB
    int t = threadIdx.x;
    int lane = t & 63;
    int w = t >> 6;
#pragma unroll
    for (int p = 0; p < 8; ++p) {
        int g = p * 512 + t;
        Bsh[g] = Wg[g];
    }
    __syncthreads();

    int n16 = lane & 15, quad = lane >> 4;
    float bhv[8], bgv[8];
#pragma unroll
    for (int h = 0; h < 8; ++h) {
        bhv[h] = b_edge[h * 16 + n16];
        bgv[h] = b_gate[h * 16 + n16];
    }

    int gw = blockIdx.x * 8 + w;   // 0..4095
    int tile = gw;

    float4 f[8];
    const float* ar0 = EF + ((size_t)tile * 16 + n16) * 128 + quad * 8;
#pragma unroll
    for (int kk = 0; kk < 4; ++kk) {
        f[2 * kk]     = *(const float4*)(ar0 + kk * 32);
        f[2 * kk + 1] = *(const float4*)(ar0 + kk * 32 + 4);
    }

    while (tile < NTILES) {
        int next = tile + NWAVES_K2;
        bf16x8 af[4];
#pragma unroll
        for (int kk = 0; kk < 4; ++kk) {
            float4 f0 = f[2 * kk], f1 = f[2 * kk + 1];
            bf16x8 v;
            v[0] = (__bf16)f0.x; v[1] = (__bf16)f0.y; v[2] = (__bf16)f0.z; v[3] = (__bf16)f0.w;
            v[4] = (__bf16)f1.x; v[5] = (__bf16)f1.y; v[6] = (__bf16)f1.z; v[7] = (__bf16)f1.w;
            af[kk] = v;
        }
        if (next < NTILES) {
            const float* ar = EF + ((size_t)next * 16 + n16) * 128 + quad * 8;
#pragma unroll
            for (int kk = 0; kk < 4; ++kk) {
                f[2 * kk]     = *(const float4*)(ar + kk * 32);
                f[2 * kk + 1] = *(const float4*)(ar + kk * 32 + 4);
            }
        }

        f32x4 acc[8][2];
        f32x4 zero = {0.f, 0.f, 0.f, 0.f};
#pragma unroll
        for (int h = 0; h < 8; ++h) { acc[h][0] = zero; acc[h][1] = zero; }
#pragma unroll
        for (int kk = 0; kk < 4; ++kk) {
#pragma unroll
            for (int h = 0; h < 8; ++h) {
                bf16x8 bh = Bsh[(h * 4 + kk) * 64 + lane];
                bf16x8 bg = Bsh[((8 + h) * 4 + kk) * 64 + lane];
                acc[h][0] = __builtin_amdgcn_mfma_f32_16x16x32_bf16(af[kk], bh, acc[h][0], 0, 0, 0);
                acc[h][1] = __builtin_amdgcn_mfma_f32_16x16x32_bf16(af[kk], bg, acc[h][1], 0, 0, 0);
            }
        }

        size_t e0 = (size_t)tile * 16;
        int b = (tile >= NTILES / 2) ? 1 : 0;
        int local0 = (int)(e0 - (size_t)b * LOCAL_E);
        const int* adjp = adj + (size_t)b * LOCAL_E + local0 + quad * 4;
        int av0 = adjp[0], av1 = adjp[1], av2 = adjp[2], av3 = adjp[3];
#pragma unroll
        for (int h = 0; h < 8; ++h) {
            float vr[4];
#pragma unroll
            for (int r = 0; r < 4; ++r) {
                float hv = acc[h][0][r] + bhv[h];
                float gv = acc[h][1][r] + bgv[h];
                float v = hv * (1.f / (1.f + __expf(-gv)));
                v += __shfl_xor(v, 1);
                v += __shfl_xor(v, 2);
                v += __shfl_xor(v, 4);
                v += __shfl_xor(v, 8);
                vr[r] = v;
            }
            if (n16 == 0) {
                float4 o;
                o.x = av0 ? vr[0] : -1e9f;
                o.y = av1 ? vr[1] : -1e9f;
                o.z = av2 ? vr[2] : -1e9f;
                o.w = av3 ? vr[3] : -1e9f;
                *(float4*)(ea + ((size_t)(b * 8 + h)) * LOCAL_E + local0 + quad * 4) = o;
            }
        }
        tile = next;
    }
}

// ---------------------------------------------------------------------------
// K3: scores = QK^T/4 + ea (pre-masked), softmax, attn_out = attn@V.
// Writes attn probabilities to ws. One barrier per block.
// ---------------------------------------------------------------------------
__global__ __launch_bounds__(256) void k3_attn(
    const float* __restrict__ Q, const float* __restrict__ K, const float* __restrict__ V,
    const float* __restrict__ ea, float* __restrict__ attn,
    float* __restrict__ attn_out)
{
    __shared__ float Kt[16 * 385];
    __shared__ float Vt[16 * 385];
    __shared__ float Qi[256];
    __shared__ float prow[4][384];
    int t = threadIdx.x;
    int bh = blockIdx.x / 24;
    int chunk = blockIdx.x % 24;
    int b = bh >> 3, h = bh & 7;
    const float* Kbase = K + (size_t)bh * NN * HD;
    const float* Vbase = V + (size_t)bh * NN * HD;
    for (int p = 0; p < 24; ++p) {
        int idx = p * 256 + t;
        int j = idx >> 4, d = idx & 15;
        Kt[d * 385 + j] = Kbase[idx];
        Vt[d * 385 + j] = Vbase[idx];
    }
    Qi[t] = Q[(size_t)bh * NN * HD + chunk * 256 + t];
    __syncthreads();

    int lane = t & 63, w = t >> 6;
    for (int ri = 0; ri < 4; ++ri) {
        int r_local = w * 4 + ri;
        int i = chunk * 16 + r_local;
        float4 q0 = *(const float4*)&Qi[r_local * 16 + 0];
        float4 q1 = *(const float4*)&Qi[r_local * 16 + 4];
        float4 q2 = *(const float4*)&Qi[r_local * 16 + 8];
        float4 q3 = *(const float4*)&Qi[r_local * 16 + 12];
        const float* eaI = ea + (size_t)bh * LOCAL_E + (size_t)i * NN;
        float s[6];
#pragma unroll
        for (int jj = 0; jj < 6; ++jj) {
            int j = jj * 64 + lane;
            float a = 0.f;
            a += q0.x * Kt[0 * 385 + j];  a += q0.y * Kt[1 * 385 + j];
            a += q0.z * Kt[2 * 385 + j];  a += q0.w * Kt[3 * 385 + j];
            a += q1.x * Kt[4 * 385 + j];  a += q1.y * Kt[5 * 385 + j];
            a += q1.z * Kt[6 * 385 + j];  a += q1.w * Kt[7 * 385 + j];
            a += q2.x * Kt[8 * 385 + j];  a += q2.y * Kt[9 * 385 + j];
            a += q2.z * Kt[10 * 385 + j]; a += q2.w * Kt[11 * 385 + j];
            a += q3.x * Kt[12 * 385 + j]; a += q3.y * Kt[13 * 385 + j];
            a += q3.z * Kt[14 * 385 + j]; a += q3.w * Kt[15 * 385 + j];
            s[jj] = a * 0.25f + eaI[j];
        }
        float mx = s[0];
#pragma unroll
        for (int jj = 1; jj < 6; ++jj) mx = fmaxf(mx, s[jj]);
#pragma unroll
        for (int o = 1; o < 64; o <<= 1) mx = fmaxf(mx, __shfl_xor(mx, o));
        float sm = 0.f;
        float e[6];
#pragma unroll
        for (int jj = 0; jj < 6; ++jj) { e[jj] = __expf(s[jj] - mx); sm += e[jj]; }
#pragma unroll
        for (int o = 1; o < 64; o <<= 1) sm += __shfl_xor(sm, o);
        float inv = 1.f / sm;
        float* attnI = attn + (size_t)bh * LOCAL_E + (size_t)i * NN;
#pragma unroll
        for (int jj = 0; jj < 6; ++jj) {
            float p = e[jj] * inv;
            attnI[jj * 64 + lane] = p;
            prow[w][jj * 64 + lane] = p;
        }
        int d = lane & 15, g = lane >> 4;
        float o = 0.f;
#pragma unroll
        for (int jt = 0; jt < 24; ++jt) {
            int j = g * 96 + jt * 4;
            float4 pp = *(const float4*)&prow[w][j];
            o += pp.x * Vt[d * 385 + j]     + pp.y * Vt[d * 385 + j + 1]
               + pp.z * Vt[d * 385 + j + 2] + pp.w * Vt[d * 385 + j + 3];
        }
        o += __shfl_xor(o, 16);
        o += __shfl_xor(o, 32);
        if (lane < 16)
            attn_out[((size_t)b * NN + i) * HIDDIM + h * HD + d] = o;
    }
}

// ---------------------------------------------------------------------------
// K5: h_new = LN(residual + attn_out@W_out + b_out); hp = h_new@W_eout
// ---------------------------------------------------------------------------
__global__ __launch_bounds__(128) void k5_hout(
    const float* __restrict__ attn_out, const float* __restrict__ h_res,
    const float* __restrict__ W_out, const float* __restrict__ b_out,
    const float* __restrict__ g1, const float* __restrict__ be1,
    const float* __restrict__ W_eout,
    float* __restrict__ h_out, float* __restrict__ hp)
{
    __shared__ float ao[8][128];
    __shared__ float hn[8][128];
    __shared__ float redA[2], redB[2];
    int t = threadIdx.x, r0 = blockIdx.x * 8;
    for (int r = 0; r < 8; ++r) ao[r][t] = attn_out[(size_t)(r0 + r) * 128 + t];
    __syncthreads();
    float acc[8];
#pragma unroll
    for (int r = 0; r < 8; ++r) acc[r] = b_out[t];
    for (int k = 0; k < 128; ++k) {
        float w = W_out[k * 128 + t];
#pragma unroll
        for (int r = 0; r < 8; ++r) acc[r] += ao[r][k] * w;
    }
    int lane = t & 63, wid = t >> 6;
    float gg = g1[t], bb = be1[t];
    for (int r = 0; r < 8; ++r) {
        float u = h_res[(size_t)(r0 + r) * 128 + t] + acc[r];
        float sv = u, sq = u * u;
#pragma unroll
        for (int o = 1; o < 64; o <<= 1) { sv += __shfl_xor(sv, o); sq += __shfl_xor(sq, o); }
        if (lane == 0) { redA[wid] = sv; redB[wid] = sq; }
        __syncthreads();
        float tot = redA[0] + redA[1], totq = redB[0] + redB[1];
        __syncthreads();
        float mean = tot * (1.f / 128.f);
        float var = totq * (1.f / 128.f) - mean * mean;
        float nv = (u - mean) * rsqrtf(var + 1e-5f) * gg + bb;
        h_out[(size_t)(r0 + r) * 128 + t] = nv;
        hn[r][t] = nv;
    }
    __syncthreads();
    float acc2[8];
#pragma unroll
    for (int r = 0; r < 8; ++r) acc2[r] = 0.f;
    for (int k = 0; k < 128; ++k) {
        float w = W_eout[k * 128 + t];
#pragma unroll
        for (int r = 0; r < 8; ++r) acc2[r] += hn[r][k] * w;
    }
    for (int r = 0; r < 8; ++r) hp[(size_t)(r0 + r) * 128 + t] = acc2[r];
}

// ---------------------------------------------------------------------------
// K6: edge_out = LN(edge_feat + mean_h(attn)*0.5*(hp_i+hp_j) + b_eout)
// ---------------------------------------------------------------------------
__global__ __launch_bounds__(256) void k6_eout(
    const float* __restrict__ EF, const float* __restrict__ attn,
    const float* __restrict__ hp, const float* __restrict__ b_eout,
    const float* __restrict__ g2, const float* __restrict__ be2,
    float* __restrict__ eout)
{
    int t = threadIdx.x;
    int slot = t >> 5, l = t & 31;
    size_t e = (size_t)blockIdx.x * 8 + slot;
    int b = (int)(e / LOCAL_E);
    int local = (int)(e - (size_t)b * LOCAL_E);
    int i = local / NN, j = local - i * NN;
    float av = 0.f;
    if (l < 8) av = attn[((size_t)(b * 8 + l)) * LOCAL_E + local];
    av += __shfl_xor(av, 1, 32);
    av += __shfl_xor(av, 2, 32);
    av += __shfl_xor(av, 4, 32);
    float a = __shfl(av, 0, 32) * 0.125f;
    const float4* ef4 = (const float4*)(EF + e * 128);
    const float4* hpi = (const float4*)(hp + (size_t)(b * NN + i) * 128);
    const float4* hpj = (const float4*)(hp + (size_t)(b * NN + j) * 128);
    float4 ef = ef4[l];
    float4 pi = hpi[l], pj = hpj[l];
    float4 bo = ((const float4*)b_eout)[l];
    float4 u;
    u.x = ef.x + a * 0.5f * (pi.x + pj.x) + bo.x;
    u.y = ef.y + a * 0.5f * (pi.y + pj.y) + bo.y;
    u.z = ef.z + a * 0.5f * (pi.z + pj.z) + bo.z;
    u.w = ef.w + a * 0.5f * (pi.w + pj.w) + bo.w;
    float sv = u.x + u.y + u.z + u.w;
    float sq = u.x * u.x + u.y * u.y + u.z * u.z + u.w * u.w;
#pragma unroll
    for (int o = 1; o < 32; o <<= 1) { sv += __shfl_xor(sv, o, 32); sq += __shfl_xor(sq, o, 32); }
    float mean = sv * (1.f / 128.f);
    float var = sq * (1.f / 128.f) - mean * mean;
    float rs = rsqrtf(var + 1e-5f);
    float4 gg = ((const float4*)g2)[l], bb = ((const float4*)be2)[l];
    float4 o4;
    o4.x = (u.x - mean) * rs * gg.x + bb.x;
    o4.y = (u.y - mean) * rs * gg.y + bb.y;
    o4.z = (u.z - mean) * rs * gg.z + bb.z;
    o4.w = (u.w - mean) * rs * gg.w + bb.w;
    ((float4*)(eout + e * 128))[l] = o4;
}

extern "C" void kernel_launch(void* const* d_in, const int* in_sizes, int n_in,
                              void* d_out, int out_size, void* d_ws, size_t ws_size,
                              hipStream_t stream) {
    (void)in_sizes; (void)n_in; (void)out_size; (void)ws_size;
    const float* nf     = (const float*)d_in[0];
    const float* ef     = (const float*)d_in[1];
    const int*   adj    = (const int*)d_in[2];
    const float* W_node = (const float*)d_in[3];
    const float* b_node = (const float*)d_in[4];
    const float* W_q    = (const float*)d_in[5];
    const float* b_q    = (const float*)d_in[6];
    const float* W_k    = (const float*)d_in[7];
    const float* b_k    = (const float*)d_in[8];
    const float* W_v    = (const float*)d_in[9];
    const float* b_v    = (const float*)d_in[10];
    const float* W_edge = (const float*)d_in[11];
    const float* b_edge = (const float*)d_in[12];
    const float* W_gate = (const float*)d_in[13];
    const float* b_gate = (const float*)d_in[14];
    const float* W_out  = (const float*)d_in[15];
    const float* b_out  = (const float*)d_in[16];
    const float* W_eout = (const float*)d_in[17];
    const float* b_eout = (const float*)d_in[18];
    const float* g1     = (const float*)d_in[19];
    const float* be1    = (const float*)d_in[20];
    const float* g2     = (const float*)d_in[21];
    const float* be2    = (const float*)d_in[22];

    float* ws = (float*)d_ws;
    float* h_res    = ws;                  //  98304
    float* Q        = ws + 98304;          //  98304
    float* Kp       = ws + 196608;         //  98304
    float* Vp       = ws + 294912;         //  98304
    float* attn_out = ws + 393216;         //  98304
    float* hp       = ws + 491520;         //  98304
    bf16x8* Wg      = (bf16x8*)(ws + 589824);  // 65536 B
    float* attn     = ws + 606208;         // 2359296 floats (9.4 MB)

    float* h_out = (float*)d_out;                  // output 0: (B,N,HID)
    float* eout  = (float*)d_out + 98304;          // output 1: (B,N,N,EDGE_DIM)
    float* ea = eout;  // masked edge_attn parked in edge output, K6 overwrites

    prep_w<<<dim3(16), dim3(256), 0, stream>>>(W_edge, W_gate, Wg);
    k1_proj<<<dim3(96), dim3(128), 0, stream>>>(nf, W_node, b_node, W_q, b_q,
                                                W_k, b_k, W_v, b_v, h_res, Q, Kp, Vp);
    k2_edge<<<dim3(512), dim3(512), 0, stream>>>(ef, Wg, b_edge, b_gate, adj, ea);
    k3_attn<<<dim3(384), dim3(256), 0, stream>>>(Q, Kp, Vp, ea, attn, attn_out);
    k5_hout<<<dim3(96), dim3(128), 0, stream>>>(attn_out, h_res, W_out, b_out,
                                                g1, be1, W_eout, h_out, hp);
    k6_eout<<<dim3(36864), dim3(256), 0, stream>>>(ef, attn, hp, b_eout, g2, be2, eout);
}